// Round 1
// baseline (329.325 us; speedup 1.0000x reference)
//
#include <hip/hip_runtime.h>
#include <hip/hip_cooperative_groups.h>
#include <stdint.h>

namespace cg = cooperative_groups;

// Problem constants (fixed by the reference)
#define DDIM    20
#define SLATE   5
#define KSEL    100
#define HID     256
#define SAMPN   16384                // prefix-sample size (docs are iid)
#define NSH     8                    // atomic shards / merge-lists
#define SHCAP   1024                 // per-shard candidate capacity
#define RCAP    8192                 // recovery candidate capacity per slate
#define STP     128                  // shard-top stride (pad of KSEL)
#define OUT_IDX_OFF (SLATE * KSEL * DDIM)   // 10000

// Workspace byte offsets
#define WS_PROTO   0                 // f64[100]
#define WS_PROTOF  1024              // f32[100]
#define WS_TP2     1536              // u16[5]  T10+2
#define WS_TM2     1556              // u16[5]  T10-2
#define WS_THI     1576              // u16[5]  sample rank-100 key
#define WS_SHCNT   1600              // u32[40] stride-16 (64B lines)  <- zeroed in phase A / mlp
#define WS_STRICT  4160              // u32[40] stride-16              <- zeroed
#define WS_CNT2    6720              // u32[5]  stride-16              <- zeroed
#define WS_ZEND    7040              // end of zeroed region
#define WS_SKEYS   8192              // u16[5*SAMPN]                 -> 172032
#define WS_CAND    172032            // u32[5][NSH][SHCAP]           -> 335872
#define WS_CAND2   335872            // u32[5][RCAP]                 -> 499712
#define WS_STD2    499712            // f64[5][NSH][STP]             -> 540672
#define WS_STIX    540672            // u32[5][NSH][STP]             -> 561152
#define WS_STLEN   561152            // u32[5][NSH]                  -> 561312

// ---- exact-order f64 distance: UNCHANGED from all passing rounds ----
__device__ __forceinline__ double dleaky(double x) { return x >= 0.0 ? x : 0.01 * x; }

__device__ __forceinline__ double calc_d2(const float* doc, const double* p) {
    double acc = 0.0;
#pragma unroll
    for (int i = 0; i < DDIM; ++i) {
        double d = (double)doc[i] - p[i];
        acc = fma(d, d, acc);
    }
    return acc;
}

__device__ __forceinline__ void load_doc(const float* __restrict__ docs,
                                         size_t n, float* doc) {
    const float4* dp = (const float4*)(docs + n * DDIM);
    float4 v0 = dp[0], v1 = dp[1], v2 = dp[2], v3 = dp[3], v4 = dp[4];
    doc[0] = v0.x; doc[1] = v0.y; doc[2] = v0.z; doc[3] = v0.w;
    doc[4] = v1.x; doc[5] = v1.y; doc[6] = v1.z; doc[7] = v1.w;
    doc[8] = v2.x; doc[9] = v2.y; doc[10] = v2.z; doc[11] = v2.w;
    doc[12] = v3.x; doc[13] = v3.y; doc[14] = v3.z; doc[15] = v3.w;
    doc[16] = v4.x; doc[17] = v4.y; doc[18] = v4.z; doc[19] = v4.w;
}

// Shared guard: pure function of counters — identical everywhere it is used.
__device__ __forceinline__ int slate_use_primary(
    const unsigned* __restrict__ shardCnt, const unsigned* __restrict__ strictSh,
    int s) {
    unsigned strictTot = 0; bool ovf = false;
    for (int sh = 0; sh < NSH; ++sh) {
        if (shardCnt[(sh * SLATE + s) * 16] > SHCAP) ovf = true;
        strictTot += strictSh[(sh * SLATE + s) * 16];
    }
    return (strictTot >= KSEL) && !ovf;
}

// ===========================================================================
// FUSED cooperative kernel: the whole 7-kernel pipeline in ONE dispatch.
// Rationale (rocprof): sum of per-kernel execution ~40us vs 103us end-to-end;
// the gap is 6 dependent graph-node boundaries (~10us each) + single-block
// latency phases. 4 grid syncs (~3-5us each) replace them.
// LDS phases are non-overlapping in time -> one union, max ~13.7 KB.
// __launch_bounds__(256,4): <=128 VGPR -> 4 blocks/CU guaranteed resident.
// ===========================================================================

struct SmMlp  { double xs[DDIM]; double h1[HID]; double h2[HID]; double ps[SLATE * DDIM]; };
struct SmSel  { unsigned wsum[2][4]; };
struct SmCmp  { float psf[SLATE * DDIM]; unsigned short ktp[SLATE]; unsigned short ktm[SLATE]; };
struct SmRec  { double ps[SLATE * DDIM]; unsigned short kt[SLATE]; int act[SLATE]; int anyAct; };
struct SmRank { double ld[SHCAP]; double outD2[KSEL]; double ps[DDIM];
                unsigned li[SHCAP]; unsigned outIx[KSEL];
                unsigned c; const unsigned* src; };
struct SmMrg  { double md[NSH * KSEL]; unsigned mi[NSH * KSEL];
                unsigned Ls[NSH]; unsigned offs[NSH + 1]; unsigned sel[KSEL]; };
union SmU { SmMlp mlp; SmSel sel; SmCmp cmp; SmRec rec; SmRank rank; SmMrg mrg; };

__global__ __launch_bounds__(256, 4) void fused_kernel(
    const float* __restrict__ x0, const float* __restrict__ docs,
    const float* __restrict__ W1, const float* __restrict__ b1,
    const float* __restrict__ W2, const float* __restrict__ b2,
    const float* __restrict__ W3, const float* __restrict__ b3,
    double* __restrict__ proto, float* __restrict__ protof,
    unsigned short* __restrict__ Tp2, unsigned short* __restrict__ Tm2,
    unsigned short* __restrict__ Thi,
    unsigned* __restrict__ shardCnt, unsigned* __restrict__ strictSh,
    unsigned* __restrict__ cnt2, unsigned short* __restrict__ skeys,
    unsigned* __restrict__ candIdx, unsigned* __restrict__ candIdx2,
    double* __restrict__ stD2, unsigned* __restrict__ stIx,
    unsigned* __restrict__ stLen, float* __restrict__ out, int N) {
    cg::grid_group grid = cg::this_grid();
    const int bid  = blockIdx.x;
    const int t    = threadIdx.x;
    const int nblk = gridDim.x;
    __shared__ SmU sm;

    // ---------------- Phase A: redundant MLP (blocks 0..63) + sample keys ---
    // Every sampling block recomputes the tiny f64 MLP itself (W2 is L2-shared
    // after the first miss) -> no grid dependency on a single mlp block.
    if (bid < SAMPN / 256) {
        SmMlp& M = sm.mlp;
        if (t < DDIM) M.xs[t] = (double)x0[t];
        __syncthreads();
        {
            double acc = 0.0;
#pragma unroll
            for (int i = 0; i < DDIM; ++i) acc = fma(M.xs[i], (double)W1[t * DDIM + i], acc);
            acc += (double)b1[t];
            M.h1[t] = dleaky(acc);
        }
        __syncthreads();
        {
            double acc = 0.0;
            for (int i = 0; i < HID; ++i) acc = fma(M.h1[i], (double)W2[t * HID + i], acc);
            acc += (double)b2[t];
            M.h2[t] = dleaky(acc);
        }
        __syncthreads();
        if (t < SLATE * DDIM) {
            double acc = 0.0;
            for (int i = 0; i < HID; ++i) acc = fma(M.h2[i], (double)W3[t * HID + i], acc);
            acc += (double)b3[t];
            double v = dleaky(acc);
            M.ps[t] = v;
            if (bid == 0) { proto[t] = v; protof[t] = (float)v; }   // for later phases
        }
        __syncthreads();
        int i = bid * 256 + t;                         // exactly covers SAMPN
        if (i < N) {
            float doc[DDIM];
            load_doc(docs, (size_t)i, doc);
#pragma unroll
            for (int s = 0; s < SLATE; ++s) {
                double d2 = calc_d2(doc, M.ps + s * DDIM);
                skeys[s * SAMPN + i] = (unsigned short)(__float_as_uint((float)d2) >> 16);
            }
        }
    } else if (bid == SAMPN / 256) {
        // zero counters (WS_SHCNT..WS_ZEND): 1360 words, replaces hipMemsetAsync
        for (int i = t; i < 1360; i += 256) shardCnt[i] = 0u;
    }
    grid.sync();   // skeys + proto/protof + zeroed counters visible

    // ---------------- Phase B: dual binary search (blocks 0..4) -------------
    if (bid < SLATE) {
        const int s = bid, lane = t & 63, w = t >> 6;
        const unsigned* kp = (const unsigned*)(skeys + (size_t)s * SAMPN);
        unsigned kw[32];
#pragma unroll
        for (int j = 0; j < 32; ++j) kw[j] = kp[j * 256 + t];   // coalesced

        unsigned X10 = 0, X100 = 0;
        int buf = 0;
        for (int b = 15; b >= 0; --b) {
            unsigned p10 = X10 | (1u << b), p100 = X100 | (1u << b);
            int c10 = 0, c100 = 0;
#pragma unroll
            for (int j = 0; j < 32; ++j) {
                unsigned lo = kw[j] & 0xffffu, hi = kw[j] >> 16;
                c10  += (lo < p10)  + (hi < p10);
                c100 += (lo < p100) + (hi < p100);
            }
#pragma unroll
            for (int off = 32; off; off >>= 1) {
                c10  += __shfl_down(c10, off);
                c100 += __shfl_down(c100, off);
            }
            if (lane == 0) sm.sel.wsum[buf][w] = (unsigned)c10 | ((unsigned)c100 << 16);
            __syncthreads();
            unsigned t10 = 0, t100 = 0;
            for (int i = 0; i < 4; ++i) {
                unsigned v = sm.sel.wsum[buf][i];
                t10 += v & 0xffffu; t100 += v >> 16;
            }
            if ((int)t10 < 10)   X10 = p10;
            if ((int)t100 < 100) X100 = p100;
            buf ^= 1;
        }
        if (t == 0) {
            unsigned tp = X10 + 2u; if (tp > 65535u) tp = 65535u;
            Tp2[s] = (unsigned short)tp;
            Tm2[s] = (unsigned short)(X10 >= 2u ? X10 - 2u : 0u);
            Thi[s] = (unsigned short)X100;
        }
    }
    grid.sync();   // thresholds visible

    // ---------------- Phase C: f32 bulk filter (ALL blocks, grid-stride) ----
    {
        SmCmp& C = sm.cmp;
        if (t < SLATE * DDIM) C.psf[t] = protof[t];
        if (t < SLATE) { C.ktp[t] = Tp2[t]; C.ktm[t] = Tm2[t]; }
        __syncthreads();
        const int lane = t & 63;
        const int sh = bid & (NSH - 1);
        for (int base = bid * 256; base < N; base += nblk * 256) {
            int n = base + t;
            bool dv = n < N;                // NO early break: ballots need full wave
            float doc[DDIM];
            if (dv) load_doc(docs, (size_t)n, doc);
            else {
#pragma unroll
                for (int i = 0; i < DDIM; ++i) doc[i] = 0.f;
            }
            float acc[SLATE] = {0.f, 0.f, 0.f, 0.f, 0.f};
#pragma unroll
            for (int i = 0; i < DDIM; ++i) {
                float dvi = doc[i];
#pragma unroll
                for (int s = 0; s < SLATE; ++s) {
                    float d = dvi - C.psf[s * DDIM + i];
                    acc[s] = fmaf(d, d, acc[s]);   // f32 FILTER only; f64 redone later
                }
            }
#pragma unroll
            for (int s = 0; s < SLATE; ++s) {
                unsigned k32 = __float_as_uint(acc[s]) >> 16;
                bool hit = dv && k32 <= (unsigned)C.ktp[s];
                unsigned long long ms = __ballot(dv && k32 <= (unsigned)C.ktm[s]);
                if (ms) {
                    int ldr = __ffsll(ms) - 1;
                    if (lane == ldr)
                        atomicAdd(&strictSh[(sh * SLATE + s) * 16], (unsigned)__popcll(ms));
                }
                unsigned long long mh = __ballot(hit);
                if (mh) {
                    int ldr = __ffsll(mh) - 1;
                    unsigned base2 = 0;
                    if (lane == ldr)
                        base2 = atomicAdd(&shardCnt[(sh * SLATE + s) * 16], (unsigned)__popcll(mh));
                    base2 = __shfl(base2, ldr);
                    if (hit) {
                        unsigned pos = base2 + (unsigned)__popcll(mh & ((1ull << lane) - 1ull));
                        if (pos < SHCAP)
                            candIdx[((size_t)(s * NSH + sh)) * SHCAP + pos] = (unsigned)n;
                    }
                }
            }
        }
    }
    grid.sync();   // candidate lists + counters final

    // ---------------- Phase D: recovery (uniform no-op unless guard fails) --
    {
        SmRec& R = sm.rec;
        if (t == 0) {
            int any = 0;
            for (int s = 0; s < SLATE; ++s) {
                int a = slate_use_primary(shardCnt, strictSh, s) ? 0 : 1;
                R.act[s] = a; any |= a;
            }
            R.anyAct = any;     // pure fn of global counters -> identical in every block
        }
        __syncthreads();
        if (R.anyAct) {         // uniformly-taken branch -> conditional grid.sync is legal
            if (t < SLATE) R.kt[t] = Thi[t];
            if (t < SLATE * DDIM) R.ps[t] = proto[t];
            __syncthreads();
            for (int n = bid * 256 + t; n < N; n += nblk * 256) {
                float doc[DDIM];
                load_doc(docs, (size_t)n, doc);
                for (int s = 0; s < SLATE; ++s) {
                    if (!R.act[s]) continue;
                    double d2 = calc_d2(doc, R.ps + s * DDIM);
                    unsigned key = __float_as_uint((float)d2) >> 16;
                    if (key <= (unsigned)R.kt[s]) {
                        unsigned pos = atomicAdd(&cnt2[s * 16], 1u);
                        if (pos < RCAP) candIdx2[(size_t)s * RCAP + pos] = (unsigned)n;
                    }
                }
            }
            grid.sync();
        }
    }

    // ---------------- Phase E: per-(slate,shard) exact f64 top-100 ----------
    if (bid < NSH * SLATE) {
        const int sh = bid & (NSH - 1), s = bid >> 3;
        SmRank& K = sm.rank;
        if (t < DDIM) K.ps[t] = proto[s * DDIM + t];
        if (t == 0) {
            if (slate_use_primary(shardCnt, strictSh, s)) {
                unsigned c = shardCnt[(sh * SLATE + s) * 16];
                if (c > SHCAP) c = SHCAP;              // unreachable in primary mode
                K.c = c;
                K.src = candIdx + ((size_t)(s * NSH + sh)) * SHCAP;
            } else {
                unsigned c2 = cnt2[s * 16]; if (c2 > RCAP) c2 = RCAP;
                unsigned L = (c2 + NSH - 1) / NSH;
                unsigned lo = sh * L, hi = lo + L;
                if (lo > c2) lo = c2;
                if (hi > c2) hi = c2;
                K.c = hi - lo;
                K.src = candIdx2 + (size_t)s * RCAP + lo;
            }
        }
        __syncthreads();
        unsigned c = K.c;
        const unsigned* src = K.src;

        for (unsigned i = t; i < c; i += 256) {
            unsigned idx = src[i];
            K.li[i] = idx;
            float doc[DDIM];
            load_doc(docs, (size_t)idx, doc);
            K.ld[i] = calc_d2(doc, K.ps);              // canonical exact d2
        }
        __syncthreads();

        // exact local rank by (d2, idx); rank<KSEL lands in sorted output slot
        for (unsigned e = t; e < c; e += 256) {
            double de = K.ld[e]; unsigned ie = K.li[e];
            unsigned rank = 0;
            for (unsigned j = 0; j < c; ++j) {
                double dj = K.ld[j]; unsigned ij = K.li[j];
                rank += (dj < de) || (dj == de && ij < ie);
            }
            if (rank < KSEL) { K.outD2[rank] = de; K.outIx[rank] = ie; }
        }
        __syncthreads();

        unsigned L = c < KSEL ? c : KSEL;
        size_t base = (size_t)(s * NSH + sh) * STP;
        for (unsigned r = t; r < L; r += 256) {
            stD2[base + r] = K.outD2[r];
            stIx[base + r] = K.outIx[r];
        }
        if (t == 0) stLen[s * NSH + sh] = L;
    }
    grid.sync();   // sorted shard lists visible

    // ---------------- Phase F: merge 8 sorted lists + outputs (blocks 0..4) -
    if (bid < SLATE) {
        const int s = bid;
        SmMrg& G = sm.mrg;
        if (t < NSH) G.Ls[t] = stLen[s * NSH + t];
        __syncthreads();
        if (t == 0) {
            unsigned o = 0;
            for (int sh = 0; sh < NSH; ++sh) { G.offs[sh] = o; o += G.Ls[sh]; }
            G.offs[NSH] = o;
        }
        __syncthreads();
        for (int sh = 0; sh < NSH; ++sh) {
            unsigned L = G.Ls[sh];
            for (unsigned i = t; i < L; i += 256) {
                G.md[sh * KSEL + i] = stD2[(size_t)(s * NSH + sh) * STP + i];
                G.mi[sh * KSEL + i] = stIx[(size_t)(s * NSH + sh) * STP + i];
            }
        }
        __syncthreads();

        unsigned S = G.offs[NSH];
        for (unsigned e = t; e < S; e += 256) {
            int sh = 0;
            while (e >= G.offs[sh + 1]) ++sh;
            unsigned i = e - G.offs[sh];
            double xd = G.md[sh * KSEL + i];
            unsigned xi = G.mi[sh * KSEL + i];
            unsigned rank = i;                        // own sorted list: i smaller
            for (int so = 0; so < NSH; ++so) {
                if (so == sh) continue;
                unsigned lo = 0, hi = G.Ls[so];
                while (lo < hi) {                     // lower_bound by (d2, idx)
                    unsigned mid = (lo + hi) >> 1;
                    double dj = G.md[so * KSEL + mid];
                    unsigned ij = G.mi[so * KSEL + mid];
                    bool less = (dj < xd) || (dj == xd && ij < xi);
                    if (less) lo = mid + 1; else hi = mid;
                }
                rank += lo;
            }
            if (rank < KSEL) G.sel[rank] = xi;
        }
        __syncthreads();

        if (t < KSEL) out[(size_t)OUT_IDX_OFF + s * KSEL + t] = (float)G.sel[t];
        for (int pos = t; pos < KSEL * DDIM; pos += 256) {
            int r = pos / DDIM, c = pos % DDIM;
            out[((size_t)s * KSEL + r) * DDIM + c] = docs[(size_t)G.sel[r] * DDIM + c];
        }
    }
}

// ===========================================================================
// FALLBACK: the proven 7-kernel pipeline, unchanged, used only if the
// cooperative launch is rejected (e.g. by graph capture).
// ===========================================================================

__global__ __launch_bounds__(256) void mlp_kernel(
    const float* __restrict__ x0,
    const float* __restrict__ W1, const float* __restrict__ b1,
    const float* __restrict__ W2, const float* __restrict__ b2,
    const float* __restrict__ W3, const float* __restrict__ b3,
    double* __restrict__ proto, float* __restrict__ protof,
    unsigned* __restrict__ zeroBase) {
    __shared__ double xs[DDIM];
    __shared__ double h1[HID];
    __shared__ double h2[HID];
    int t = threadIdx.x;
    for (int i = t; i < 1360; i += 256) zeroBase[i] = 0u;
    if (t < DDIM) xs[t] = (double)x0[t];
    __syncthreads();
    {
        double acc = 0.0;
#pragma unroll
        for (int i = 0; i < DDIM; ++i) acc = fma(xs[i], (double)W1[t * DDIM + i], acc);
        acc += (double)b1[t];
        h1[t] = dleaky(acc);
    }
    __syncthreads();
    {
        double acc = 0.0;
        for (int i = 0; i < HID; ++i) acc = fma(h1[i], (double)W2[t * HID + i], acc);
        acc += (double)b2[t];
        h2[t] = dleaky(acc);
    }
    __syncthreads();
    if (t < SLATE * DDIM) {
        double acc = 0.0;
        for (int i = 0; i < HID; ++i) acc = fma(h2[i], (double)W3[t * HID + i], acc);
        acc += (double)b3[t];
        double v = dleaky(acc);
        proto[t] = v;
        protof[t] = (float)v;
    }
}

__global__ __launch_bounds__(256) void sample_keys_kernel(
    const float* __restrict__ docs, const double* __restrict__ proto,
    unsigned short* __restrict__ skeys, int N) {
    __shared__ double ps[SLATE * DDIM];
    int t = threadIdx.x;
    if (t < SLATE * DDIM) ps[t] = proto[t];
    __syncthreads();
    int i = blockIdx.x * 256 + t;
    if (i >= SAMPN || i >= N) return;
    float doc[DDIM];
    load_doc(docs, (size_t)i, doc);
#pragma unroll
    for (int s = 0; s < SLATE; ++s) {
        double d2 = calc_d2(doc, ps + s * DDIM);
        skeys[s * SAMPN + i] = (unsigned short)(__float_as_uint((float)d2) >> 16);
    }
}

__global__ __launch_bounds__(1024) void select_kernel(
    const unsigned short* __restrict__ skeys,
    unsigned short* __restrict__ Tp2, unsigned short* __restrict__ Tm2,
    unsigned short* __restrict__ Thi) {
    int s = blockIdx.x, t = threadIdx.x;
    int lane = t & 63, w = t >> 6;
    __shared__ unsigned wsum[2][16];
    const unsigned* kp = (const unsigned*)(skeys + (size_t)s * SAMPN);
    unsigned kw[8];
#pragma unroll
    for (int j = 0; j < 8; ++j) kw[j] = kp[j * 1024 + t];

    unsigned X10 = 0, X100 = 0;
    int buf = 0;
    for (int b = 15; b >= 0; --b) {
        unsigned p10 = X10 | (1u << b), p100 = X100 | (1u << b);
        int c10 = 0, c100 = 0;
#pragma unroll
        for (int j = 0; j < 8; ++j) {
            unsigned lo = kw[j] & 0xffffu, hi = kw[j] >> 16;
            c10  += (lo < p10)  + (hi < p10);
            c100 += (lo < p100) + (hi < p100);
        }
#pragma unroll
        for (int off = 32; off; off >>= 1) {
            c10  += __shfl_down(c10, off);
            c100 += __shfl_down(c100, off);
        }
        if (lane == 0) wsum[buf][w] = (unsigned)c10 | ((unsigned)c100 << 16);
        __syncthreads();
        unsigned t10 = 0, t100 = 0;
        for (int i = 0; i < 16; ++i) {
            unsigned v = wsum[buf][i];
            t10 += v & 0xffffu; t100 += v >> 16;
        }
        if ((int)t10 < 10)   X10 = p10;
        if ((int)t100 < 100) X100 = p100;
        buf ^= 1;
    }
    if (t == 0) {
        unsigned tp = X10 + 2u; if (tp > 65535u) tp = 65535u;
        Tp2[s] = (unsigned short)tp;
        Tm2[s] = (unsigned short)(X10 >= 2u ? X10 - 2u : 0u);
        Thi[s] = (unsigned short)X100;
    }
}

__global__ __launch_bounds__(256) void compact1_kernel(
    const float* __restrict__ docs, const float* __restrict__ protof,
    const unsigned short* __restrict__ Tp2, const unsigned short* __restrict__ Tm2,
    unsigned* __restrict__ shardCnt, unsigned* __restrict__ strictSh,
    unsigned* __restrict__ candIdx, int N) {
    __shared__ float psf[SLATE * DDIM];
    __shared__ unsigned short ktp[SLATE], ktm[SLATE];
    int t = threadIdx.x;
    if (t < SLATE * DDIM) psf[t] = protof[t];
    if (t < SLATE) { ktp[t] = Tp2[t]; ktm[t] = Tm2[t]; }
    __syncthreads();

    int n = blockIdx.x * 256 + t;
    bool dv = n < N;
    int lane = t & 63;
    int sh = blockIdx.x & (NSH - 1);

    float doc[DDIM];
    if (dv) load_doc(docs, (size_t)n, doc);
    else {
#pragma unroll
        for (int i = 0; i < DDIM; ++i) doc[i] = 0.f;
    }
    float acc[SLATE] = {0.f, 0.f, 0.f, 0.f, 0.f};
#pragma unroll
    for (int i = 0; i < DDIM; ++i) {
        float dvi = doc[i];
#pragma unroll
        for (int s = 0; s < SLATE; ++s) {
            float d = dvi - psf[s * DDIM + i];
            acc[s] = fmaf(d, d, acc[s]);
        }
    }
#pragma unroll
    for (int s = 0; s < SLATE; ++s) {
        unsigned k32 = __float_as_uint(acc[s]) >> 16;
        bool hit = dv && k32 <= (unsigned)ktp[s];
        unsigned long long ms = __ballot(dv && k32 <= (unsigned)ktm[s]);
        if (ms) {
            int ldr = __ffsll(ms) - 1;
            if (lane == ldr)
                atomicAdd(&strictSh[(sh * SLATE + s) * 16], (unsigned)__popcll(ms));
        }
        unsigned long long mh = __ballot(hit);
        if (mh) {
            int ldr = __ffsll(mh) - 1;
            unsigned base = 0;
            if (lane == ldr)
                base = atomicAdd(&shardCnt[(sh * SLATE + s) * 16], (unsigned)__popcll(mh));
            base = __shfl(base, ldr);
            if (hit) {
                unsigned pos = base + (unsigned)__popcll(mh & ((1ull << lane) - 1ull));
                if (pos < SHCAP)
                    candIdx[((size_t)(s * NSH + sh)) * SHCAP + pos] = (unsigned)n;
            }
        }
    }
}

__global__ __launch_bounds__(256) void compact2_kernel(
    const float* __restrict__ docs, const double* __restrict__ proto,
    const unsigned short* __restrict__ Thi,
    const unsigned* __restrict__ shardCnt, const unsigned* __restrict__ strictSh,
    unsigned* __restrict__ cnt2, unsigned* __restrict__ candIdx2, int N) {
    __shared__ int act[SLATE];
    __shared__ int anyAct;
    __shared__ double ps[SLATE * DDIM];
    __shared__ unsigned short kt[SLATE];
    int t = threadIdx.x;
    if (t == 0) {
        int any = 0;
        for (int s = 0; s < SLATE; ++s) {
            int a = slate_use_primary(shardCnt, strictSh, s) ? 0 : 1;
            act[s] = a; any |= a;
        }
        anyAct = any;
    }
    __syncthreads();
    if (!anyAct) return;

    if (t < SLATE) kt[t] = Thi[t];
    if (t < SLATE * DDIM) ps[t] = proto[t];
    __syncthreads();
    for (int n = blockIdx.x * 256 + t; n < N; n += gridDim.x * 256) {
        float doc[DDIM];
        load_doc(docs, (size_t)n, doc);
        for (int s = 0; s < SLATE; ++s) {
            if (!act[s]) continue;
            double d2 = calc_d2(doc, ps + s * DDIM);
            unsigned key = __float_as_uint((float)d2) >> 16;
            if (key <= (unsigned)kt[s]) {
                unsigned pos = atomicAdd(&cnt2[s * 16], 1u);
                if (pos < RCAP) candIdx2[(size_t)s * RCAP + pos] = (unsigned)n;
            }
        }
    }
}

__global__ __launch_bounds__(256) void shard_rank_kernel(
    const float* __restrict__ docs, const double* __restrict__ proto,
    const unsigned* __restrict__ shardCnt, const unsigned* __restrict__ strictSh,
    const unsigned* __restrict__ cnt2,
    const unsigned* __restrict__ candIdx, const unsigned* __restrict__ candIdx2,
    double* __restrict__ stD2, unsigned* __restrict__ stIx,
    unsigned* __restrict__ stLen, int N) {
    int sh = blockIdx.x, s = blockIdx.y;
    int t = threadIdx.x;
    __shared__ double ld[SHCAP];
    __shared__ unsigned li[SHCAP];
    __shared__ double ps[DDIM];
    __shared__ double outD2[KSEL];
    __shared__ unsigned outIx[KSEL];
    __shared__ unsigned c_s;
    __shared__ const unsigned* src_s;
    if (t < DDIM) ps[t] = proto[s * DDIM + t];
    if (t == 0) {
        if (slate_use_primary(shardCnt, strictSh, s)) {
            unsigned c = shardCnt[(sh * SLATE + s) * 16];
            if (c > SHCAP) c = SHCAP;
            c_s = c;
            src_s = candIdx + ((size_t)(s * NSH + sh)) * SHCAP;
        } else {
            unsigned c2 = cnt2[s * 16]; if (c2 > RCAP) c2 = RCAP;
            unsigned L = (c2 + NSH - 1) / NSH;
            unsigned lo = sh * L, hi = lo + L;
            if (lo > c2) lo = c2;
            if (hi > c2) hi = c2;
            c_s = hi - lo;
            src_s = candIdx2 + (size_t)s * RCAP + lo;
        }
    }
    __syncthreads();
    unsigned c = c_s;
    const unsigned* src = src_s;

    for (unsigned i = t; i < c; i += 256) {
        unsigned idx = src[i];
        li[i] = idx;
        float doc[DDIM];
        load_doc(docs, (size_t)idx, doc);
        ld[i] = calc_d2(doc, ps);
    }
    __syncthreads();

    for (unsigned e = t; e < c; e += 256) {
        double de = ld[e]; unsigned ie = li[e];
        unsigned rank = 0;
        for (unsigned j = 0; j < c; ++j) {
            double dj = ld[j]; unsigned ij = li[j];
            rank += (dj < de) || (dj == de && ij < ie);
        }
        if (rank < KSEL) { outD2[rank] = de; outIx[rank] = ie; }
    }
    __syncthreads();

    unsigned L = c < KSEL ? c : KSEL;
    size_t base = (size_t)(s * NSH + sh) * STP;
    for (unsigned r = t; r < L; r += 256) {
        stD2[base + r] = outD2[r];
        stIx[base + r] = outIx[r];
    }
    if (t == 0) stLen[s * NSH + sh] = L;
}

__global__ __launch_bounds__(1024) void merge_kernel(
    const float* __restrict__ docs,
    const double* __restrict__ stD2, const unsigned* __restrict__ stIx,
    const unsigned* __restrict__ stLen, float* __restrict__ out) {
    int s = blockIdx.x, t = threadIdx.x;
    __shared__ double md[NSH * KSEL];
    __shared__ unsigned mi[NSH * KSEL];
    __shared__ unsigned Ls[NSH], offs[NSH + 1];
    __shared__ unsigned sel[KSEL];
    if (t < NSH) Ls[t] = stLen[s * NSH + t];
    __syncthreads();
    if (t == 0) {
        unsigned o = 0;
        for (int sh = 0; sh < NSH; ++sh) { offs[sh] = o; o += Ls[sh]; }
        offs[NSH] = o;
    }
    __syncthreads();
    for (int sh = 0; sh < NSH; ++sh) {
        unsigned L = Ls[sh];
        for (unsigned i = t; i < L; i += 1024) {
            md[sh * KSEL + i] = stD2[(size_t)(s * NSH + sh) * STP + i];
            mi[sh * KSEL + i] = stIx[(size_t)(s * NSH + sh) * STP + i];
        }
    }
    __syncthreads();

    unsigned S = offs[NSH];
    for (unsigned e = t; e < S; e += 1024) {
        int sh = 0;
        while (e >= offs[sh + 1]) ++sh;
        unsigned i = e - offs[sh];
        double xd = md[sh * KSEL + i];
        unsigned xi = mi[sh * KSEL + i];
        unsigned rank = i;
        for (int so = 0; so < NSH; ++so) {
            if (so == sh) continue;
            unsigned lo = 0, hi = Ls[so];
            while (lo < hi) {
                unsigned mid = (lo + hi) >> 1;
                double dj = md[so * KSEL + mid];
                unsigned ij = mi[so * KSEL + mid];
                bool less = (dj < xd) || (dj == xd && ij < xi);
                if (less) lo = mid + 1; else hi = mid;
            }
            rank += lo;
        }
        if (rank < KSEL) sel[rank] = xi;
    }
    __syncthreads();

    if (t < KSEL) out[(size_t)OUT_IDX_OFF + s * KSEL + t] = (float)sel[t];
    for (int pos = t; pos < KSEL * DDIM; pos += 1024) {
        int r = pos / DDIM, c = pos % DDIM;
        out[((size_t)s * KSEL + r) * DDIM + c] = docs[(size_t)sel[r] * DDIM + c];
    }
}

extern "C" void kernel_launch(void* const* d_in, const int* in_sizes, int n_in,
                              void* d_out, int out_size, void* d_ws, size_t ws_size,
                              hipStream_t stream) {
    const float* x0   = (const float*)d_in[0];
    const float* docs = (const float*)d_in[1];
    const float* W1   = (const float*)d_in[2];
    const float* b1   = (const float*)d_in[3];
    const float* W2   = (const float*)d_in[4];
    const float* b2   = (const float*)d_in[5];
    const float* W3   = (const float*)d_in[6];
    const float* b3   = (const float*)d_in[7];
    int N = in_sizes[1] / DDIM;   // 1,000,000

    char* ws = (char*)d_ws;
    double*         proto    = (double*)(ws + WS_PROTO);
    float*          protof   = (float*)(ws + WS_PROTOF);
    unsigned short* Tp2      = (unsigned short*)(ws + WS_TP2);
    unsigned short* Tm2      = (unsigned short*)(ws + WS_TM2);
    unsigned short* Thi      = (unsigned short*)(ws + WS_THI);
    unsigned*       shardCnt = (unsigned*)(ws + WS_SHCNT);
    unsigned*       strictSh = (unsigned*)(ws + WS_STRICT);
    unsigned*       cnt2     = (unsigned*)(ws + WS_CNT2);
    unsigned short* skeys    = (unsigned short*)(ws + WS_SKEYS);
    unsigned*       candIdx  = (unsigned*)(ws + WS_CAND);
    unsigned*       candIdx2 = (unsigned*)(ws + WS_CAND2);
    double*         stD2     = (double*)(ws + WS_STD2);
    unsigned*       stIx     = (unsigned*)(ws + WS_STIX);
    unsigned*       stLen    = (unsigned*)(ws + WS_STLEN);
    float*          outp     = (float*)d_out;

    // One-time: co-resident grid size for the cooperative launch.
    // Host-side queries only (no allocation/sync) -> graph-capture safe.
    static int g_nblk = -1;
    if (g_nblk == -1) {
        int per_cu = 0;
        if (hipOccupancyMaxActiveBlocksPerMultiprocessor(&per_cu, fused_kernel, 256, 0)
                != hipSuccess || per_cu <= 0)
            per_cu = 0;
        int ncu = 256;   // MI355X
        int dev = 0;
        hipDeviceProp_t prop;
        if (hipGetDevice(&dev) == hipSuccess &&
            hipGetDeviceProperties(&prop, dev) == hipSuccess &&
            prop.multiProcessorCount > 0)
            ncu = prop.multiProcessorCount;
        long cap = (long)per_cu * (long)ncu;
        int nb = cap >= 1024 ? 1024 : (int)cap;
        nb &= ~7;                               // multiple of 8 for shard balance
        // need >= 65 blocks (64 sample + 1 zeroing) and >= 40 rank blocks
        g_nblk = (nb >= 72) ? nb : 0;           // 0 -> fallback pipeline
    }

    bool done = false;
    if (g_nblk > 0) {
        void* args[] = { (void*)&x0, (void*)&docs, (void*)&W1, (void*)&b1,
                         (void*)&W2, (void*)&b2, (void*)&W3, (void*)&b3,
                         (void*)&proto, (void*)&protof,
                         (void*)&Tp2, (void*)&Tm2, (void*)&Thi,
                         (void*)&shardCnt, (void*)&strictSh, (void*)&cnt2,
                         (void*)&skeys, (void*)&candIdx, (void*)&candIdx2,
                         (void*)&stD2, (void*)&stIx, (void*)&stLen,
                         (void*)&outp, (void*)&N };
        hipError_t e = hipLaunchCooperativeKernel((const void*)fused_kernel,
                                                  dim3(g_nblk), dim3(256),
                                                  args, 0, stream);
        if (e == hipSuccess) {
            done = true;
        } else {
            (void)hipGetLastError();   // clear sticky error; use fallback from now on
            g_nblk = 0;
        }
    }

    if (!done) {
        mlp_kernel<<<1, 256, 0, stream>>>(x0, W1, b1, W2, b2, W3, b3,
                                          proto, protof, shardCnt);
        sample_keys_kernel<<<SAMPN / 256, 256, 0, stream>>>(docs, proto, skeys, N);
        select_kernel<<<SLATE, 1024, 0, stream>>>(skeys, Tp2, Tm2, Thi);
        int nb = (N + 255) / 256;
        compact1_kernel<<<nb, 256, 0, stream>>>(docs, protof, Tp2, Tm2,
                                                shardCnt, strictSh, candIdx, N);
        compact2_kernel<<<1024, 256, 0, stream>>>(docs, proto, Thi, shardCnt, strictSh,
                                                  cnt2, candIdx2, N);
        shard_rank_kernel<<<dim3(NSH, SLATE), 256, 0, stream>>>(
            docs, proto, shardCnt, strictSh, cnt2, candIdx, candIdx2,
            stD2, stIx, stLen, N);
        merge_kernel<<<SLATE, 1024, 0, stream>>>(docs, stD2, stIx, stLen, outp);
    }
}

// Round 2
// 116.147 us; speedup vs baseline: 2.8354x; 2.8354x over previous
//
#include <hip/hip_runtime.h>
#include <stdint.h>
#include <math.h>

// Problem constants (fixed by the reference)
#define DDIM    20
#define SLATE   5
#define KSEL    100
#define HID     256
#define SAMPN   16384                // prefix-sample size (docs are iid)
#define NSH     8                    // atomic shards
#define SHCAP   1024                 // per-shard candidate capacity
#define RCAP    8192                 // concat / recovery candidate capacity per slate
#define CHUNK   2048                 // rank chunk held in LDS
#define OUT_IDX_OFF (SLATE * KSEL * DDIM)   // 10000

// Workspace byte offsets (layout unchanged from proven rounds)
#define WS_PROTO   0                 // f64[100]
#define WS_PROTOF  1024              // f32[100]
#define WS_TP2     1536              // u16[5]  T10+2
#define WS_TM2     1556              // u16[5]  T10-2
#define WS_THI     1576              // u16[5]  sample rank-100 key
#define WS_SHCNT   1600              // u32[40] stride-16 (64B lines)  <- zeroed in kernel 1
#define WS_STRICT  4160              // u32[40] stride-16              <- zeroed
#define WS_CNT2    6720              // u32[5]  stride-16              <- zeroed (unused now, kept)
#define WS_ZEND    7040              // end of zeroed region
#define WS_SKEYS   8192              // u16[5*SAMPN]                 -> 172032
#define WS_CAND    172032            // u32[5][NSH][SHCAP]           -> 335872
#define WS_CAND2   335872            // u32[5][RCAP]  (concat scratch) -> 499712

// ---- exact-order f64 distance: UNCHANGED from all passing rounds ----
__device__ __forceinline__ double dleaky(double x) { return x >= 0.0 ? x : 0.01 * x; }

__device__ __forceinline__ double calc_d2(const float* doc, const double* p) {
    double acc = 0.0;
#pragma unroll
    for (int i = 0; i < DDIM; ++i) {
        double d = (double)doc[i] - p[i];
        acc = fma(d, d, acc);
    }
    return acc;
}

__device__ __forceinline__ void load_doc(const float* __restrict__ docs,
                                         size_t n, float* doc) {
    const float4* dp = (const float4*)(docs + n * DDIM);
    float4 v0 = dp[0], v1 = dp[1], v2 = dp[2], v3 = dp[3], v4 = dp[4];
    doc[0] = v0.x; doc[1] = v0.y; doc[2] = v0.z; doc[3] = v0.w;
    doc[4] = v1.x; doc[5] = v1.y; doc[6] = v1.z; doc[7] = v1.w;
    doc[8] = v2.x; doc[9] = v2.y; doc[10] = v2.z; doc[11] = v2.w;
    doc[12] = v3.x; doc[13] = v3.y; doc[14] = v3.z; doc[15] = v3.w;
    doc[16] = v4.x; doc[17] = v4.y; doc[18] = v4.z; doc[19] = v4.w;
}

// Guard: pure function of counters — identical wherever it is evaluated.
__device__ __forceinline__ int slate_use_primary(
    const unsigned* __restrict__ shardCnt, const unsigned* __restrict__ strictSh,
    int s) {
    unsigned strictTot = 0; bool ovf = false;
    for (int sh = 0; sh < NSH; ++sh) {
        if (shardCnt[(sh * SLATE + s) * 16] > SHCAP) ovf = true;
        strictTot += strictSh[(sh * SLATE + s) * 16];
    }
    return (strictTot >= KSEL) && !ovf;
}

// ===========================================================================
// Kernel 1: redundant f64 MLP per sampling block + sample keys + zeroing.
// R1 lesson: cooperative grid.sync costs ~100us each on 8-XCD MI355X — fuse
// only where NO sync is needed. Each of the 64 sample blocks recomputes the
// tiny MLP itself (identical f64 ops -> bit-identical proto in every block;
// W2 is L2-resident after the first reader). Block 64 zeroes the counters
// (replaces hipMemsetAsync, rocprof showed 47us for the runtime fill).
// Removes: mlp->sample boundary + single-block MLP serialization.
// ===========================================================================
__global__ __launch_bounds__(256) void mlp_sample_kernel(
    const float* __restrict__ x0, const float* __restrict__ docs,
    const float* __restrict__ W1, const float* __restrict__ b1,
    const float* __restrict__ W2, const float* __restrict__ b2,
    const float* __restrict__ W3, const float* __restrict__ b3,
    double* __restrict__ proto, float* __restrict__ protof,
    unsigned short* __restrict__ skeys, unsigned* __restrict__ zeroBase, int N) {
    const int bid = blockIdx.x, t = threadIdx.x;
    if (bid == SAMPN / 256) {            // zeroing block: no barriers, just exit
        for (int i = t; i < 1360; i += 256) zeroBase[i] = 0u;
        return;
    }
    __shared__ double xs[DDIM];
    __shared__ double h1[HID];
    __shared__ double h2[HID];
    __shared__ double ps[SLATE * DDIM];
    if (t < DDIM) xs[t] = (double)x0[t];
    __syncthreads();
    {
        double acc = 0.0;
#pragma unroll
        for (int i = 0; i < DDIM; ++i) acc = fma(xs[i], (double)W1[t * DDIM + i], acc);
        acc += (double)b1[t];
        h1[t] = dleaky(acc);
    }
    __syncthreads();
    {
        double acc = 0.0;
        for (int i = 0; i < HID; ++i) acc = fma(h1[i], (double)W2[t * HID + i], acc);
        acc += (double)b2[t];
        h2[t] = dleaky(acc);
    }
    __syncthreads();
    if (t < SLATE * DDIM) {
        double acc = 0.0;
        for (int i = 0; i < HID; ++i) acc = fma(h2[i], (double)W3[t * HID + i], acc);
        acc += (double)b3[t];
        double v = dleaky(acc);
        ps[t] = v;
        if (bid == 0) { proto[t] = v; protof[t] = (float)v; }  // for later kernels
    }
    __syncthreads();
    int i = bid * 256 + t;               // exactly covers SAMPN
    if (i < SAMPN && i < N) {
        float doc[DDIM];
        load_doc(docs, (size_t)i, doc);
#pragma unroll
        for (int s = 0; s < SLATE; ++s) {
            double d2 = calc_d2(doc, ps + s * DDIM);
            skeys[s * SAMPN + i] = (unsigned short)(__float_as_uint((float)d2) >> 16);
        }
    }
}

// -------- Kernel 2: ONE dual binary search -> ranks 10 & 100 (unchanged) ----
__global__ __launch_bounds__(1024) void select_kernel(
    const unsigned short* __restrict__ skeys,
    unsigned short* __restrict__ Tp2, unsigned short* __restrict__ Tm2,
    unsigned short* __restrict__ Thi) {
    int s = blockIdx.x, t = threadIdx.x;
    int lane = t & 63, w = t >> 6;
    __shared__ unsigned wsum[2][16];
    const unsigned* kp = (const unsigned*)(skeys + (size_t)s * SAMPN);
    unsigned kw[8];
#pragma unroll
    for (int j = 0; j < 8; ++j) kw[j] = kp[j * 1024 + t];   // coalesced

    unsigned X10 = 0, X100 = 0;
    int buf = 0;
    for (int b = 15; b >= 0; --b) {
        unsigned p10 = X10 | (1u << b), p100 = X100 | (1u << b);
        int c10 = 0, c100 = 0;
#pragma unroll
        for (int j = 0; j < 8; ++j) {
            unsigned lo = kw[j] & 0xffffu, hi = kw[j] >> 16;
            c10  += (lo < p10)  + (hi < p10);
            c100 += (lo < p100) + (hi < p100);
        }
#pragma unroll
        for (int off = 32; off; off >>= 1) {
            c10  += __shfl_down(c10, off);
            c100 += __shfl_down(c100, off);
        }
        if (lane == 0) wsum[buf][w] = (unsigned)c10 | ((unsigned)c100 << 16);
        __syncthreads();
        unsigned t10 = 0, t100 = 0;
        for (int i = 0; i < 16; ++i) {
            unsigned v = wsum[buf][i];
            t10 += v & 0xffffu; t100 += v >> 16;
        }
        if ((int)t10 < 10)   X10 = p10;
        if ((int)t100 < 100) X100 = p100;
        buf ^= 1;
    }
    if (t == 0) {
        unsigned tp = X10 + 2u; if (tp > 65535u) tp = 65535u;
        Tp2[s] = (unsigned short)tp;
        Tm2[s] = (unsigned short)(X10 >= 2u ? X10 - 2u : 0u);
        Thi[s] = (unsigned short)X100;   // >=100 docs qualify: the samples themselves
    }
}

// -------- Kernel 3: f32 bulk filter, sharded wave-aggregated atomics --------
// (verbatim from the proven 103us round)
__global__ __launch_bounds__(256) void compact1_kernel(
    const float* __restrict__ docs, const float* __restrict__ protof,
    const unsigned short* __restrict__ Tp2, const unsigned short* __restrict__ Tm2,
    unsigned* __restrict__ shardCnt, unsigned* __restrict__ strictSh,
    unsigned* __restrict__ candIdx, int N) {
    __shared__ float psf[SLATE * DDIM];
    __shared__ unsigned short ktp[SLATE], ktm[SLATE];
    int t = threadIdx.x;
    if (t < SLATE * DDIM) psf[t] = protof[t];
    if (t < SLATE) { ktp[t] = Tp2[t]; ktm[t] = Tm2[t]; }
    __syncthreads();

    int n = blockIdx.x * 256 + t;
    bool dv = n < N;               // NO early return: ballots need full wave
    int lane = t & 63;
    int sh = blockIdx.x & (NSH - 1);

    float doc[DDIM];
    if (dv) load_doc(docs, (size_t)n, doc);
    else {
#pragma unroll
        for (int i = 0; i < DDIM; ++i) doc[i] = 0.f;
    }
    float acc[SLATE] = {0.f, 0.f, 0.f, 0.f, 0.f};
#pragma unroll
    for (int i = 0; i < DDIM; ++i) {
        float dvi = doc[i];
#pragma unroll
        for (int s = 0; s < SLATE; ++s) {
            float d = dvi - psf[s * DDIM + i];
            acc[s] = fmaf(d, d, acc[s]);   // f32 FILTER only; f64 redone later
        }
    }
#pragma unroll
    for (int s = 0; s < SLATE; ++s) {
        unsigned k32 = __float_as_uint(acc[s]) >> 16;
        bool hit = dv && k32 <= (unsigned)ktp[s];
        unsigned long long ms = __ballot(dv && k32 <= (unsigned)ktm[s]);
        if (ms) {
            int ldr = __ffsll(ms) - 1;
            if (lane == ldr)
                atomicAdd(&strictSh[(sh * SLATE + s) * 16], (unsigned)__popcll(ms));
        }
        unsigned long long mh = __ballot(hit);
        if (mh) {
            int ldr = __ffsll(mh) - 1;
            unsigned base = 0;
            if (lane == ldr)
                base = atomicAdd(&shardCnt[(sh * SLATE + s) * 16], (unsigned)__popcll(mh));
            base = __shfl(base, ldr);
            if (hit) {
                unsigned pos = base + (unsigned)__popcll(mh & ((1ull << lane) - 1ull));
                if (pos < SHCAP)
                    candIdx[((size_t)(s * NSH + sh)) * SHCAP + pos] = (unsigned)n;
            }
        }
    }
}

// ===========================================================================
// Kernel 4: rank_merge — replaces compact2 + shard_rank + merge.
// One block per slate. The guard is block-local (pure fn of counters).
// Primary: concatenate the 8 shard lists (~610 candidates expected) into the
//   per-slate scratch, then ONE exact global rank by (f64 d2, idx) — identical
//   result to per-shard-top-100 + merge-by-rank (global rank<100 implies
//   shard rank<100). Recovery (never taken in this bench, exactness kept):
//   this block scans all docs with the same exact f64/Thi filter, then ranks.
// Chunked O(c^2) rank: own elements in registers, chunk of (d2,idx) in LDS.
// ===========================================================================
template<int NOWN>
__device__ __forceinline__ void rank_select(
    const float* __restrict__ docs, const unsigned* __restrict__ lst,
    unsigned ctot, const double* ps, double* ld, unsigned* li,
    unsigned* outIx, int t) {
    double   myD2[NOWN];
    unsigned myIx[NOWN];
    unsigned myRank[NOWN];
#pragma unroll
    for (int k = 0; k < NOWN; ++k) {
        unsigned e = (unsigned)t + 1024u * (unsigned)k;
        myD2[k] = INFINITY; myIx[k] = 0xffffffffu; myRank[k] = 0u;
        if (e < ctot) {
            unsigned idx = lst[e];
            float doc[DDIM];
            load_doc(docs, (size_t)idx, doc);
            myIx[k] = idx;
            myD2[k] = calc_d2(doc, ps);
        }
    }
    for (unsigned c0 = 0; c0 < ctot; c0 += CHUNK) {
        unsigned cn = (ctot - c0) < CHUNK ? (ctot - c0) : CHUNK;
        __syncthreads();                        // protect ld/li reuse
        for (unsigned j = t; j < cn; j += 1024) {
            unsigned idx = lst[c0 + j];
            float doc[DDIM];
            load_doc(docs, (size_t)idx, doc);
            li[j] = idx;
            ld[j] = calc_d2(doc, ps);           // canonical exact d2
        }
        __syncthreads();
        for (unsigned j = 0; j < cn; ++j) {
            double dj = ld[j]; unsigned ij = li[j];
#pragma unroll
            for (int k = 0; k < NOWN; ++k)
                myRank[k] += ((dj < myD2[k]) || (dj == myD2[k] && ij < myIx[k])) ? 1u : 0u;
        }
    }
    __syncthreads();
#pragma unroll
    for (int k = 0; k < NOWN; ++k)
        if (myRank[k] < KSEL) outIx[myRank[k]] = myIx[k];
    // invalid slots have myD2=INF -> rank >= ctot >= KSEL -> never written
}

__global__ __launch_bounds__(1024) void rank_merge_kernel(
    const float* __restrict__ docs, const double* __restrict__ proto,
    const unsigned short* __restrict__ Thi,
    const unsigned* __restrict__ shardCnt, const unsigned* __restrict__ strictSh,
    const unsigned* __restrict__ candIdx, unsigned* __restrict__ scratch,
    float* __restrict__ out, int N) {
    const int s = blockIdx.x, t = threadIdx.x;
    __shared__ double   ps[DDIM];
    __shared__ double   ld[CHUNK];
    __shared__ unsigned li[CHUNK];
    __shared__ unsigned offs[NSH + 1];
    __shared__ unsigned outIx[KSEL];
    __shared__ unsigned ctot_s;
    __shared__ int      prim_s;
    __shared__ unsigned rcnt;
    if (t < DDIM) ps[t] = proto[s * DDIM + t];
    if (t == 0) {
        int p = slate_use_primary(shardCnt, strictSh, s);
        prim_s = p;
        rcnt = 0u;
        if (p) {
            unsigned o = 0;
            for (int sh = 0; sh < NSH; ++sh) {
                offs[sh] = o;
                o += shardCnt[(sh * SLATE + s) * 16];   // <= SHCAP each (guard)
            }
            offs[NSH] = o;
            ctot_s = o;                                  // <= 8192 = RCAP
        }
    }
    __syncthreads();
    unsigned* lst = scratch + (size_t)s * RCAP;
    unsigned ctot;
    if (prim_s) {
        ctot = ctot_s;
        for (unsigned e = t; e < ctot; e += 1024) {      // concat 8 shard lists
            int sh = 0;
            while (e >= offs[sh + 1]) ++sh;
            lst[e] = candIdx[((size_t)(s * NSH + sh)) * SHCAP + (e - offs[sh])];
        }
    } else {
        // exact recovery scan (same f64 key + Thi threshold as always)
        unsigned kt = Thi[s];
        for (int n = t; n < N; n += 1024) {
            float doc[DDIM];
            load_doc(docs, (size_t)n, doc);
            double d2 = calc_d2(doc, ps);
            unsigned key = __float_as_uint((float)d2) >> 16;
            if (key <= kt) {
                unsigned pos = atomicAdd(&rcnt, 1u);
                if (pos < RCAP) lst[pos] = (unsigned)n;
            }
        }
        __syncthreads();
        ctot = rcnt < RCAP ? rcnt : RCAP;
    }
    __syncthreads();   // lst[] visible block-wide (same CU, write-through L1)

    if (ctot <= 1024u)      rank_select<1>(docs, lst, ctot, ps, ld, li, outIx, t);
    else if (ctot <= 2048u) rank_select<2>(docs, lst, ctot, ps, ld, li, outIx, t);
    else if (ctot <= 4096u) rank_select<4>(docs, lst, ctot, ps, ld, li, outIx, t);
    else                    rank_select<8>(docs, lst, ctot, ps, ld, li, outIx, t);
    __syncthreads();

    if (t < KSEL) out[(size_t)OUT_IDX_OFF + s * KSEL + t] = (float)outIx[t];
    for (int pos = t; pos < KSEL * DDIM; pos += 1024) {
        int r = pos / DDIM, c = pos % DDIM;
        out[((size_t)s * KSEL + r) * DDIM + c] = docs[(size_t)outIx[r] * DDIM + c];
    }
}

extern "C" void kernel_launch(void* const* d_in, const int* in_sizes, int n_in,
                              void* d_out, int out_size, void* d_ws, size_t ws_size,
                              hipStream_t stream) {
    const float* x0   = (const float*)d_in[0];
    const float* docs = (const float*)d_in[1];
    const float* W1   = (const float*)d_in[2];
    const float* b1   = (const float*)d_in[3];
    const float* W2   = (const float*)d_in[4];
    const float* b2   = (const float*)d_in[5];
    const float* W3   = (const float*)d_in[6];
    const float* b3   = (const float*)d_in[7];
    int N = in_sizes[1] / DDIM;   // 1,000,000

    char* ws = (char*)d_ws;
    double*         proto    = (double*)(ws + WS_PROTO);
    float*          protof   = (float*)(ws + WS_PROTOF);
    unsigned short* Tp2      = (unsigned short*)(ws + WS_TP2);
    unsigned short* Tm2      = (unsigned short*)(ws + WS_TM2);
    unsigned short* Thi      = (unsigned short*)(ws + WS_THI);
    unsigned*       shardCnt = (unsigned*)(ws + WS_SHCNT);
    unsigned*       strictSh = (unsigned*)(ws + WS_STRICT);
    unsigned short* skeys    = (unsigned short*)(ws + WS_SKEYS);
    unsigned*       candIdx  = (unsigned*)(ws + WS_CAND);
    unsigned*       scratch  = (unsigned*)(ws + WS_CAND2);
    float*          outp     = (float*)d_out;

    // 4 kernels / 3 boundaries (was 7/6). No cooperative launch (R1 lesson:
    // grid.sync ~100us each on MI355X). No hipMemsetAsync (zeroing fused).
    mlp_sample_kernel<<<SAMPN / 256 + 1, 256, 0, stream>>>(
        x0, docs, W1, b1, W2, b2, W3, b3, proto, protof, skeys, shardCnt, N);
    select_kernel<<<SLATE, 1024, 0, stream>>>(skeys, Tp2, Tm2, Thi);
    int nb = (N + 255) / 256;
    compact1_kernel<<<nb, 256, 0, stream>>>(docs, protof, Tp2, Tm2,
                                            shardCnt, strictSh, candIdx, N);
    rank_merge_kernel<<<SLATE, 1024, 0, stream>>>(
        docs, proto, Thi, shardCnt, strictSh, candIdx, scratch, outp, N);
}

// Round 3
// 106.936 us; speedup vs baseline: 3.0796x; 1.0861x over previous
//
#include <hip/hip_runtime.h>
#include <stdint.h>
#include <math.h>

// Problem constants (fixed by the reference)
#define DDIM    20
#define SLATE   5
#define KSEL    100
#define HID     256
#define SAMPN   16384                // prefix-sample size (docs are iid)
#define NSH     8                    // atomic shards
#define SHCAP   1024                 // per-shard candidate capacity
#define RCAP    8192                 // recovery scratch per slate (8 slices x 1024)
#define STP     128                  // shard-top stride (pad of KSEL)
#define OUT_IDX_OFF (SLATE * KSEL * DDIM)   // 10000

// Workspace byte offsets
#define WS_PROTO   0                 // f64[100]
#define WS_PROTOF  1024              // f32[100]
#define WS_TP2     1536              // u16[5]  T10+2
#define WS_TM2     1556              // u16[5]  T10-2
#define WS_THI     1576              // u16[5]  sample rank-100 key
#define WS_SHCNT   1600              // u32[40] stride-16 (64B lines)  <- zeroed in kernel 1
#define WS_STRICT  4160              // u32[40] stride-16              <- zeroed
#define WS_CNT2    6720              // u32[5]  stride-16 doneCnt      <- zeroed
#define WS_ZEND    7040              // end of zeroed region
#define WS_SKEYS   8192              // u16[5*SAMPN]                 -> 172032
#define WS_CAND    172032            // u32[5][NSH][SHCAP]           -> 335872
#define WS_CAND2   335872            // u32[5][NSH][1024] recovery   -> 499712
#define WS_STD2    499712            // f64[5][NSH][STP]             -> 540672
#define WS_STIX    540672            // u32[5][NSH][STP]             -> 561152
#define WS_STLEN   561152            // u32[5][NSH]                  -> 561312

// ---- exact-order f64 distance: UNCHANGED from all passing rounds ----
__device__ __forceinline__ double dleaky(double x) { return x >= 0.0 ? x : 0.01 * x; }

__device__ __forceinline__ double calc_d2(const float* doc, const double* p) {
    double acc = 0.0;
#pragma unroll
    for (int i = 0; i < DDIM; ++i) {
        double d = (double)doc[i] - p[i];
        acc = fma(d, d, acc);
    }
    return acc;
}

__device__ __forceinline__ void load_doc(const float* __restrict__ docs,
                                         size_t n, float* doc) {
    const float4* dp = (const float4*)(docs + n * DDIM);
    float4 v0 = dp[0], v1 = dp[1], v2 = dp[2], v3 = dp[3], v4 = dp[4];
    doc[0] = v0.x; doc[1] = v0.y; doc[2] = v0.z; doc[3] = v0.w;
    doc[4] = v1.x; doc[5] = v1.y; doc[6] = v1.z; doc[7] = v1.w;
    doc[8] = v2.x; doc[9] = v2.y; doc[10] = v2.z; doc[11] = v2.w;
    doc[12] = v3.x; doc[13] = v3.y; doc[14] = v3.z; doc[15] = v3.w;
    doc[16] = v4.x; doc[17] = v4.y; doc[18] = v4.z; doc[19] = v4.w;
}

// Guard: pure function of counters — identical wherever it is evaluated.
__device__ __forceinline__ int slate_use_primary(
    const unsigned* __restrict__ shardCnt, const unsigned* __restrict__ strictSh,
    int s) {
    unsigned strictTot = 0; bool ovf = false;
    for (int sh = 0; sh < NSH; ++sh) {
        if (shardCnt[(sh * SLATE + s) * 16] > SHCAP) ovf = true;
        strictTot += strictSh[(sh * SLATE + s) * 16];
    }
    return (strictTot >= KSEL) && !ovf;
}

// ===========================================================================
// Kernel 1: redundant f64 MLP per sampling block + sample keys + zeroing.
// (unchanged from R2 — each sample block recomputes the tiny MLP bit-
// identically; block 64 zeroes counters, replacing hipMemsetAsync.)
// ===========================================================================
__global__ __launch_bounds__(256) void mlp_sample_kernel(
    const float* __restrict__ x0, const float* __restrict__ docs,
    const float* __restrict__ W1, const float* __restrict__ b1,
    const float* __restrict__ W2, const float* __restrict__ b2,
    const float* __restrict__ W3, const float* __restrict__ b3,
    double* __restrict__ proto, float* __restrict__ protof,
    unsigned short* __restrict__ skeys, unsigned* __restrict__ zeroBase, int N) {
    const int bid = blockIdx.x, t = threadIdx.x;
    if (bid == SAMPN / 256) {            // zeroing block: no barriers, just exit
        for (int i = t; i < 1360; i += 256) zeroBase[i] = 0u;
        return;
    }
    __shared__ double xs[DDIM];
    __shared__ double h1[HID];
    __shared__ double h2[HID];
    __shared__ double ps[SLATE * DDIM];
    if (t < DDIM) xs[t] = (double)x0[t];
    __syncthreads();
    {
        double acc = 0.0;
#pragma unroll
        for (int i = 0; i < DDIM; ++i) acc = fma(xs[i], (double)W1[t * DDIM + i], acc);
        acc += (double)b1[t];
        h1[t] = dleaky(acc);
    }
    __syncthreads();
    {
        double acc = 0.0;
        for (int i = 0; i < HID; ++i) acc = fma(h1[i], (double)W2[t * HID + i], acc);
        acc += (double)b2[t];
        h2[t] = dleaky(acc);
    }
    __syncthreads();
    if (t < SLATE * DDIM) {
        double acc = 0.0;
        for (int i = 0; i < HID; ++i) acc = fma(h2[i], (double)W3[t * HID + i], acc);
        acc += (double)b3[t];
        double v = dleaky(acc);
        ps[t] = v;
        if (bid == 0) { proto[t] = v; protof[t] = (float)v; }  // for later kernels
    }
    __syncthreads();
    int i = bid * 256 + t;               // exactly covers SAMPN
    if (i < SAMPN && i < N) {
        float doc[DDIM];
        load_doc(docs, (size_t)i, doc);
#pragma unroll
        for (int s = 0; s < SLATE; ++s) {
            double d2 = calc_d2(doc, ps + s * DDIM);
            skeys[s * SAMPN + i] = (unsigned short)(__float_as_uint((float)d2) >> 16);
        }
    }
}

// -------- Kernel 2: ONE dual binary search -> ranks 10 & 100 (unchanged) ----
__global__ __launch_bounds__(1024) void select_kernel(
    const unsigned short* __restrict__ skeys,
    unsigned short* __restrict__ Tp2, unsigned short* __restrict__ Tm2,
    unsigned short* __restrict__ Thi) {
    int s = blockIdx.x, t = threadIdx.x;
    int lane = t & 63, w = t >> 6;
    __shared__ unsigned wsum[2][16];
    const unsigned* kp = (const unsigned*)(skeys + (size_t)s * SAMPN);
    unsigned kw[8];
#pragma unroll
    for (int j = 0; j < 8; ++j) kw[j] = kp[j * 1024 + t];   // coalesced

    unsigned X10 = 0, X100 = 0;
    int buf = 0;
    for (int b = 15; b >= 0; --b) {
        unsigned p10 = X10 | (1u << b), p100 = X100 | (1u << b);
        int c10 = 0, c100 = 0;
#pragma unroll
        for (int j = 0; j < 8; ++j) {
            unsigned lo = kw[j] & 0xffffu, hi = kw[j] >> 16;
            c10  += (lo < p10)  + (hi < p10);
            c100 += (lo < p100) + (hi < p100);
        }
#pragma unroll
        for (int off = 32; off; off >>= 1) {
            c10  += __shfl_down(c10, off);
            c100 += __shfl_down(c100, off);
        }
        if (lane == 0) wsum[buf][w] = (unsigned)c10 | ((unsigned)c100 << 16);
        __syncthreads();
        unsigned t10 = 0, t100 = 0;
        for (int i = 0; i < 16; ++i) {
            unsigned v = wsum[buf][i];
            t10 += v & 0xffffu; t100 += v >> 16;
        }
        if ((int)t10 < 10)   X10 = p10;
        if ((int)t100 < 100) X100 = p100;
        buf ^= 1;
    }
    if (t == 0) {
        unsigned tp = X10 + 2u; if (tp > 65535u) tp = 65535u;
        Tp2[s] = (unsigned short)tp;
        Tm2[s] = (unsigned short)(X10 >= 2u ? X10 - 2u : 0u);
        Thi[s] = (unsigned short)X100;   // >=100 docs qualify: the samples themselves
    }
}

// -------- Kernel 3: f32 bulk filter, sharded wave-aggregated atomics --------
// (verbatim from the proven 103us round)
__global__ __launch_bounds__(256) void compact1_kernel(
    const float* __restrict__ docs, const float* __restrict__ protof,
    const unsigned short* __restrict__ Tp2, const unsigned short* __restrict__ Tm2,
    unsigned* __restrict__ shardCnt, unsigned* __restrict__ strictSh,
    unsigned* __restrict__ candIdx, int N) {
    __shared__ float psf[SLATE * DDIM];
    __shared__ unsigned short ktp[SLATE], ktm[SLATE];
    int t = threadIdx.x;
    if (t < SLATE * DDIM) psf[t] = protof[t];
    if (t < SLATE) { ktp[t] = Tp2[t]; ktm[t] = Tm2[t]; }
    __syncthreads();

    int n = blockIdx.x * 256 + t;
    bool dv = n < N;               // NO early return: ballots need full wave
    int lane = t & 63;
    int sh = blockIdx.x & (NSH - 1);

    float doc[DDIM];
    if (dv) load_doc(docs, (size_t)n, doc);
    else {
#pragma unroll
        for (int i = 0; i < DDIM; ++i) doc[i] = 0.f;
    }
    float acc[SLATE] = {0.f, 0.f, 0.f, 0.f, 0.f};
#pragma unroll
    for (int i = 0; i < DDIM; ++i) {
        float dvi = doc[i];
#pragma unroll
        for (int s = 0; s < SLATE; ++s) {
            float d = dvi - psf[s * DDIM + i];
            acc[s] = fmaf(d, d, acc[s]);   // f32 FILTER only; f64 redone later
        }
    }
#pragma unroll
    for (int s = 0; s < SLATE; ++s) {
        unsigned k32 = __float_as_uint(acc[s]) >> 16;
        bool hit = dv && k32 <= (unsigned)ktp[s];
        unsigned long long ms = __ballot(dv && k32 <= (unsigned)ktm[s]);
        if (ms) {
            int ldr = __ffsll(ms) - 1;
            if (lane == ldr)
                atomicAdd(&strictSh[(sh * SLATE + s) * 16], (unsigned)__popcll(ms));
        }
        unsigned long long mh = __ballot(hit);
        if (mh) {
            int ldr = __ffsll(mh) - 1;
            unsigned base = 0;
            if (lane == ldr)
                base = atomicAdd(&shardCnt[(sh * SLATE + s) * 16], (unsigned)__popcll(mh));
            base = __shfl(base, ldr);
            if (hit) {
                unsigned pos = base + (unsigned)__popcll(mh & ((1ull << lane) - 1ull));
                if (pos < SHCAP)
                    candIdx[((size_t)(s * NSH + sh)) * SHCAP + pos] = (unsigned)n;
            }
        }
    }
}

// ===========================================================================
// Kernel 4: rank_fused — per-(slate,shard) exact f64 top-100 (40 blocks, the
// proven-fast geometry: inner rank loop c~76) PLUS the merge fused in via the
// "last block done" pattern (threadfence + device-scope atomic; guide G12/G16).
// R2 lesson: 5-block mega-rank serialized a 610-iteration LDS-latency chain
// (51us); R1 lesson: grid.sync costs ~100us — this uses neither.
// Recovery path (guard failed; never taken in this bench): each shard block
// scans its own 1/8 doc slice with the exact f64/Thi filter, ranks its slice
// top-100 — per-slice top-100 + merge is exact for the global top-100.
// ===========================================================================
__global__ __launch_bounds__(256) void rank_fused_kernel(
    const float* __restrict__ docs, const double* __restrict__ proto,
    const unsigned short* __restrict__ Thi,
    const unsigned* __restrict__ shardCnt, const unsigned* __restrict__ strictSh,
    const unsigned* __restrict__ candIdx, unsigned* __restrict__ rscratch,
    double* __restrict__ stD2, unsigned* __restrict__ stIx,
    unsigned* __restrict__ stLen, unsigned* __restrict__ doneCnt,
    float* __restrict__ out, int N) {
    const int sh = blockIdx.x, s = blockIdx.y, t = threadIdx.x;
    __shared__ double   ld[SHCAP];        // rank stage: cand d2 | merge stage: md[8][100]
    __shared__ unsigned li[SHCAP];        // rank stage: cand idx | merge stage: mi[8][100]
    __shared__ double   ps[DDIM];
    __shared__ double   outD2[KSEL];
    __shared__ unsigned outIx[KSEL];      // merge stage reuse: sel[]
    __shared__ unsigned Ls[NSH], offs[NSH + 1];
    __shared__ unsigned c_s, rcnt;
    __shared__ int      prim_s, last_s;

    if (t < DDIM) ps[t] = proto[s * DDIM + t];
    if (t == 0) { prim_s = slate_use_primary(shardCnt, strictSh, s); rcnt = 0u; }
    __syncthreads();

    // ---- gather candidates for this (s,sh) into LDS with exact f64 d2 ----
    unsigned c;
    if (prim_s) {
        if (t == 0) {
            unsigned cc = shardCnt[(sh * SLATE + s) * 16];
            c_s = cc > SHCAP ? SHCAP : cc;          // unreachable clamp (guard)
        }
        __syncthreads();
        c = c_s;
        const unsigned* src = candIdx + ((size_t)(s * NSH + sh)) * SHCAP;
        for (unsigned i = t; i < c; i += 256) {
            unsigned idx = src[i];
            li[i] = idx;
            float doc[DDIM];
            load_doc(docs, (size_t)idx, doc);
            ld[i] = calc_d2(doc, ps);               // canonical exact d2
        }
    } else {
        // exact recovery scan over this block's doc slice
        unsigned kt = Thi[s];
        unsigned* lst = rscratch + (size_t)s * RCAP + (size_t)sh * SHCAP;
        int lo = (int)((long long)N * sh / NSH);
        int hi = (int)((long long)N * (sh + 1) / NSH);
        for (int n = lo + t; n < hi; n += 256) {
            float doc[DDIM];
            load_doc(docs, (size_t)n, doc);
            double d2 = calc_d2(doc, ps);
            unsigned key = __float_as_uint((float)d2) >> 16;
            if (key <= kt) {
                unsigned pos = atomicAdd(&rcnt, 1u);
                if (pos < SHCAP) lst[pos] = (unsigned)n;
            }
        }
        __syncthreads();
        c = rcnt < SHCAP ? rcnt : SHCAP;
        for (unsigned i = t; i < c; i += 256) {
            unsigned idx = lst[i];
            li[i] = idx;
            float doc[DDIM];
            load_doc(docs, (size_t)idx, doc);
            ld[i] = calc_d2(doc, ps);
        }
    }
    __syncthreads();

    // ---- exact local rank by (d2, idx); rank<KSEL -> sorted output slot ----
    for (unsigned e = t; e < c; e += 256) {
        double de = ld[e]; unsigned ie = li[e];
        unsigned rank = 0;
        for (unsigned j = 0; j < c; ++j) {
            double dj = ld[j]; unsigned ij = li[j];
            rank += (dj < de) || (dj == de && ij < ie);
        }
        if (rank < KSEL) { outD2[rank] = de; outIx[rank] = ie; }
    }
    __syncthreads();

    unsigned L = c < KSEL ? c : KSEL;
    size_t base = (size_t)(s * NSH + sh) * STP;
    for (unsigned r = t; r < L; r += 256) {
        stD2[base + r] = outD2[r];
        stIx[base + r] = outIx[r];
    }
    if (t == 0) stLen[s * NSH + sh] = L;

    // ---- last-done block of this slate performs the merge (fused) ----------
    __threadfence();                 // device-scope release of stD2/stIx/stLen
    __syncthreads();
    if (t == 0) {
        unsigned old = atomicAdd(&doneCnt[s * 16], 1u);   // device-scope (G12)
        last_s = (old == NSH - 1);
    }
    __syncthreads();
    if (!last_s) return;
    __threadfence();                 // acquire side before reading peers' lists

    // merge 8 sorted lists by binary-search rank (old merge_kernel, 256 thr)
    if (t < NSH) Ls[t] = stLen[s * NSH + t];
    __syncthreads();
    if (t == 0) {
        unsigned o = 0;
        for (int so = 0; so < NSH; ++so) { offs[so] = o; o += Ls[so]; }
        offs[NSH] = o;
    }
    __syncthreads();
    for (int so = 0; so < NSH; ++so) {
        unsigned Lx = Ls[so];
        for (unsigned i = t; i < Lx; i += 256) {
            ld[so * KSEL + i] = stD2[(size_t)(s * NSH + so) * STP + i];
            li[so * KSEL + i] = stIx[(size_t)(s * NSH + so) * STP + i];
        }
    }
    __syncthreads();

    unsigned S = offs[NSH];
    for (unsigned e = t; e < S; e += 256) {
        int so = 0;
        while (e >= offs[so + 1]) ++so;
        unsigned i = e - offs[so];
        double xd = ld[so * KSEL + i];
        unsigned xi = li[so * KSEL + i];
        unsigned rank = i;                        // own sorted list: i smaller
        for (int so2 = 0; so2 < NSH; ++so2) {
            if (so2 == so) continue;
            unsigned lo = 0, hi = Ls[so2];
            while (lo < hi) {                     // lower_bound by (d2, idx)
                unsigned mid = (lo + hi) >> 1;
                double dj = ld[so2 * KSEL + mid];
                unsigned ij = li[so2 * KSEL + mid];
                bool less = (dj < xd) || (dj == xd && ij < xi);
                if (less) lo = mid + 1; else hi = mid;
            }
            rank += lo;
        }
        if (rank < KSEL) outIx[rank] = xi;        // reuse outIx as sel[]
    }
    __syncthreads();

    if (t < KSEL) out[(size_t)OUT_IDX_OFF + s * KSEL + t] = (float)outIx[t];
    for (int pos = t; pos < KSEL * DDIM; pos += 256) {
        int r = pos / DDIM, cc = pos % DDIM;
        out[((size_t)s * KSEL + r) * DDIM + cc] = docs[(size_t)outIx[r] * DDIM + cc];
    }
}

extern "C" void kernel_launch(void* const* d_in, const int* in_sizes, int n_in,
                              void* d_out, int out_size, void* d_ws, size_t ws_size,
                              hipStream_t stream) {
    const float* x0   = (const float*)d_in[0];
    const float* docs = (const float*)d_in[1];
    const float* W1   = (const float*)d_in[2];
    const float* b1   = (const float*)d_in[3];
    const float* W2   = (const float*)d_in[4];
    const float* b2   = (const float*)d_in[5];
    const float* W3   = (const float*)d_in[6];
    const float* b3   = (const float*)d_in[7];
    int N = in_sizes[1] / DDIM;   // 1,000,000

    char* ws = (char*)d_ws;
    double*         proto    = (double*)(ws + WS_PROTO);
    float*          protof   = (float*)(ws + WS_PROTOF);
    unsigned short* Tp2      = (unsigned short*)(ws + WS_TP2);
    unsigned short* Tm2      = (unsigned short*)(ws + WS_TM2);
    unsigned short* Thi      = (unsigned short*)(ws + WS_THI);
    unsigned*       shardCnt = (unsigned*)(ws + WS_SHCNT);
    unsigned*       strictSh = (unsigned*)(ws + WS_STRICT);
    unsigned*       doneCnt  = (unsigned*)(ws + WS_CNT2);
    unsigned short* skeys    = (unsigned short*)(ws + WS_SKEYS);
    unsigned*       candIdx  = (unsigned*)(ws + WS_CAND);
    unsigned*       rscratch = (unsigned*)(ws + WS_CAND2);
    double*         stD2     = (double*)(ws + WS_STD2);
    unsigned*       stIx     = (unsigned*)(ws + WS_STIX);
    unsigned*       stLen    = (unsigned*)(ws + WS_STLEN);
    float*          outp     = (float*)d_out;

    // 4 kernels / 3 boundaries. No cooperative launch (R1: grid.sync ~100us).
    // No hipMemsetAsync (zeroing fused into kernel 1; doneCnt is in the
    // zeroed region so rocprof replays re-arm correctly).
    mlp_sample_kernel<<<SAMPN / 256 + 1, 256, 0, stream>>>(
        x0, docs, W1, b1, W2, b2, W3, b3, proto, protof, skeys, shardCnt, N);
    select_kernel<<<SLATE, 1024, 0, stream>>>(skeys, Tp2, Tm2, Thi);
    int nb = (N + 255) / 256;
    compact1_kernel<<<nb, 256, 0, stream>>>(docs, protof, Tp2, Tm2,
                                            shardCnt, strictSh, candIdx, N);
    rank_fused_kernel<<<dim3(NSH, SLATE), 256, 0, stream>>>(
        docs, proto, Thi, shardCnt, strictSh, candIdx, rscratch,
        stD2, stIx, stLen, doneCnt, outp, N);
}

// Round 4
// 92.383 us; speedup vs baseline: 3.5648x; 1.1575x over previous
//
#include <hip/hip_runtime.h>
#include <stdint.h>
#include <math.h>

// Problem constants (fixed by the reference)
#define DDIM    20
#define SLATE   5
#define KSEL    100
#define HID     256
#define SAMPN   16384                // prefix-sample size (docs are iid)
#define NSH     8                    // atomic shards
#define SHCAP   1024                 // per-shard candidate capacity
#define RCAP    8192                 // recovery scratch per slate (8 slices x 1024)
#define STP     128                  // shard-top stride (pad of KSEL)
#define OUT_IDX_OFF (SLATE * KSEL * DDIM)   // 10000

// Workspace byte offsets
#define WS_PROTO   0                 // f64[100]
#define WS_PROTOF  1024              // f32[100]
#define WS_TP2     1536              // u16[5]  T10+2
#define WS_TM2     1556              // u16[5]  T10-2
#define WS_THI     1576              // u16[5]  sample rank-100 key
#define WS_SHCNT   1600              // u32[40] stride-16 (64B lines)  <- zeroed in kernel 1
#define WS_STRICT  4160              // u32[40] stride-16              <- zeroed
#define WS_CNT2    6720              // u32[5]  stride-16 (unused)     <- zeroed
#define WS_ZEND    7040              // end of zeroed region
#define WS_SKEYS   8192              // u16[5*SAMPN]                 -> 172032
#define WS_CAND    172032            // u32[5][NSH][SHCAP]           -> 335872
#define WS_CAND2   335872            // u32[5][NSH][1024] recovery   -> 499712
#define WS_STD2    499712            // f64[5][NSH][STP]             -> 540672
#define WS_STIX    540672            // u32[5][NSH][STP]             -> 561152
#define WS_STLEN   561152            // u32[5][NSH]                  -> 561312

// ---- exact-order f64 distance: UNCHANGED from all passing rounds ----
__device__ __forceinline__ double dleaky(double x) { return x >= 0.0 ? x : 0.01 * x; }

__device__ __forceinline__ double calc_d2(const float* doc, const double* p) {
    double acc = 0.0;
#pragma unroll
    for (int i = 0; i < DDIM; ++i) {
        double d = (double)doc[i] - p[i];
        acc = fma(d, d, acc);
    }
    return acc;
}

__device__ __forceinline__ void load_doc(const float* __restrict__ docs,
                                         size_t n, float* doc) {
    const float4* dp = (const float4*)(docs + n * DDIM);
    float4 v0 = dp[0], v1 = dp[1], v2 = dp[2], v3 = dp[3], v4 = dp[4];
    doc[0] = v0.x; doc[1] = v0.y; doc[2] = v0.z; doc[3] = v0.w;
    doc[4] = v1.x; doc[5] = v1.y; doc[6] = v1.z; doc[7] = v1.w;
    doc[8] = v2.x; doc[9] = v2.y; doc[10] = v2.z; doc[11] = v2.w;
    doc[12] = v3.x; doc[13] = v3.y; doc[14] = v3.z; doc[15] = v3.w;
    doc[16] = v4.x; doc[17] = v4.y; doc[18] = v4.z; doc[19] = v4.w;
}

// Guard: pure function of counters — identical wherever it is evaluated.
__device__ __forceinline__ int slate_use_primary(
    const unsigned* __restrict__ shardCnt, const unsigned* __restrict__ strictSh,
    int s) {
    unsigned strictTot = 0; bool ovf = false;
    for (int sh = 0; sh < NSH; ++sh) {
        if (shardCnt[(sh * SLATE + s) * 16] > SHCAP) ovf = true;
        strictTot += strictSh[(sh * SLATE + s) * 16];
    }
    return (strictTot >= KSEL) && !ovf;
}

// ===========================================================================
// Kernel 1: redundant f64 MLP per sampling block + sample keys + zeroing.
// (proven in R2/R3 — each sample block recomputes the tiny MLP bit-
// identically; block 64 zeroes counters, replacing hipMemsetAsync.)
// ===========================================================================
__global__ __launch_bounds__(256) void mlp_sample_kernel(
    const float* __restrict__ x0, const float* __restrict__ docs,
    const float* __restrict__ W1, const float* __restrict__ b1,
    const float* __restrict__ W2, const float* __restrict__ b2,
    const float* __restrict__ W3, const float* __restrict__ b3,
    double* __restrict__ proto, float* __restrict__ protof,
    unsigned short* __restrict__ skeys, unsigned* __restrict__ zeroBase, int N) {
    const int bid = blockIdx.x, t = threadIdx.x;
    if (bid == SAMPN / 256) {            // zeroing block: no barriers, just exit
        for (int i = t; i < 1360; i += 256) zeroBase[i] = 0u;
        return;
    }
    __shared__ double xs[DDIM];
    __shared__ double h1[HID];
    __shared__ double h2[HID];
    __shared__ double ps[SLATE * DDIM];
    if (t < DDIM) xs[t] = (double)x0[t];
    __syncthreads();
    {
        double acc = 0.0;
#pragma unroll
        for (int i = 0; i < DDIM; ++i) acc = fma(xs[i], (double)W1[t * DDIM + i], acc);
        acc += (double)b1[t];
        h1[t] = dleaky(acc);
    }
    __syncthreads();
    {
        double acc = 0.0;
        for (int i = 0; i < HID; ++i) acc = fma(h1[i], (double)W2[t * HID + i], acc);
        acc += (double)b2[t];
        h2[t] = dleaky(acc);
    }
    __syncthreads();
    if (t < SLATE * DDIM) {
        double acc = 0.0;
        for (int i = 0; i < HID; ++i) acc = fma(h2[i], (double)W3[t * HID + i], acc);
        acc += (double)b3[t];
        double v = dleaky(acc);
        ps[t] = v;
        if (bid == 0) { proto[t] = v; protof[t] = (float)v; }  // for later kernels
    }
    __syncthreads();
    int i = bid * 256 + t;               // exactly covers SAMPN
    if (i < SAMPN && i < N) {
        float doc[DDIM];
        load_doc(docs, (size_t)i, doc);
#pragma unroll
        for (int s = 0; s < SLATE; ++s) {
            double d2 = calc_d2(doc, ps + s * DDIM);
            skeys[s * SAMPN + i] = (unsigned short)(__float_as_uint((float)d2) >> 16);
        }
    }
}

// -------- Kernel 2: ONE dual binary search -> ranks 10 & 100 (unchanged) ----
__global__ __launch_bounds__(1024) void select_kernel(
    const unsigned short* __restrict__ skeys,
    unsigned short* __restrict__ Tp2, unsigned short* __restrict__ Tm2,
    unsigned short* __restrict__ Thi) {
    int s = blockIdx.x, t = threadIdx.x;
    int lane = t & 63, w = t >> 6;
    __shared__ unsigned wsum[2][16];
    const unsigned* kp = (const unsigned*)(skeys + (size_t)s * SAMPN);
    unsigned kw[8];
#pragma unroll
    for (int j = 0; j < 8; ++j) kw[j] = kp[j * 1024 + t];   // coalesced

    unsigned X10 = 0, X100 = 0;
    int buf = 0;
    for (int b = 15; b >= 0; --b) {
        unsigned p10 = X10 | (1u << b), p100 = X100 | (1u << b);
        int c10 = 0, c100 = 0;
#pragma unroll
        for (int j = 0; j < 8; ++j) {
            unsigned lo = kw[j] & 0xffffu, hi = kw[j] >> 16;
            c10  += (lo < p10)  + (hi < p10);
            c100 += (lo < p100) + (hi < p100);
        }
#pragma unroll
        for (int off = 32; off; off >>= 1) {
            c10  += __shfl_down(c10, off);
            c100 += __shfl_down(c100, off);
        }
        if (lane == 0) wsum[buf][w] = (unsigned)c10 | ((unsigned)c100 << 16);
        __syncthreads();
        unsigned t10 = 0, t100 = 0;
        for (int i = 0; i < 16; ++i) {
            unsigned v = wsum[buf][i];
            t10 += v & 0xffffu; t100 += v >> 16;
        }
        if ((int)t10 < 10)   X10 = p10;
        if ((int)t100 < 100) X100 = p100;
        buf ^= 1;
    }
    if (t == 0) {
        unsigned tp = X10 + 2u; if (tp > 65535u) tp = 65535u;
        Tp2[s] = (unsigned short)tp;
        Tm2[s] = (unsigned short)(X10 >= 2u ? X10 - 2u : 0u);
        Thi[s] = (unsigned short)X100;   // >=100 docs qualify: the samples themselves
    }
}

// -------- Kernel 3: f32 bulk filter, sharded wave-aggregated atomics --------
// (verbatim from the proven 103us round)
__global__ __launch_bounds__(256) void compact1_kernel(
    const float* __restrict__ docs, const float* __restrict__ protof,
    const unsigned short* __restrict__ Tp2, const unsigned short* __restrict__ Tm2,
    unsigned* __restrict__ shardCnt, unsigned* __restrict__ strictSh,
    unsigned* __restrict__ candIdx, int N) {
    __shared__ float psf[SLATE * DDIM];
    __shared__ unsigned short ktp[SLATE], ktm[SLATE];
    int t = threadIdx.x;
    if (t < SLATE * DDIM) psf[t] = protof[t];
    if (t < SLATE) { ktp[t] = Tp2[t]; ktm[t] = Tm2[t]; }
    __syncthreads();

    int n = blockIdx.x * 256 + t;
    bool dv = n < N;               // NO early return: ballots need full wave
    int lane = t & 63;
    int sh = blockIdx.x & (NSH - 1);

    float doc[DDIM];
    if (dv) load_doc(docs, (size_t)n, doc);
    else {
#pragma unroll
        for (int i = 0; i < DDIM; ++i) doc[i] = 0.f;
    }
    float acc[SLATE] = {0.f, 0.f, 0.f, 0.f, 0.f};
#pragma unroll
    for (int i = 0; i < DDIM; ++i) {
        float dvi = doc[i];
#pragma unroll
        for (int s = 0; s < SLATE; ++s) {
            float d = dvi - psf[s * DDIM + i];
            acc[s] = fmaf(d, d, acc[s]);   // f32 FILTER only; f64 redone later
        }
    }
#pragma unroll
    for (int s = 0; s < SLATE; ++s) {
        unsigned k32 = __float_as_uint(acc[s]) >> 16;
        bool hit = dv && k32 <= (unsigned)ktp[s];
        unsigned long long ms = __ballot(dv && k32 <= (unsigned)ktm[s]);
        if (ms) {
            int ldr = __ffsll(ms) - 1;
            if (lane == ldr)
                atomicAdd(&strictSh[(sh * SLATE + s) * 16], (unsigned)__popcll(ms));
        }
        unsigned long long mh = __ballot(hit);
        if (mh) {
            int ldr = __ffsll(mh) - 1;
            unsigned base = 0;
            if (lane == ldr)
                base = atomicAdd(&shardCnt[(sh * SLATE + s) * 16], (unsigned)__popcll(mh));
            base = __shfl(base, ldr);
            if (hit) {
                unsigned pos = base + (unsigned)__popcll(mh & ((1ull << lane) - 1ull));
                if (pos < SHCAP)
                    candIdx[((size_t)(s * NSH + sh)) * SHCAP + pos] = (unsigned)n;
            }
        }
    }
}

// ===========================================================================
// Kernel 4: per-(slate,shard) exact f64 top-100 (40 blocks), with compact2's
// recovery scan folded in (each shard block scans its own 1/8 doc slice on
// guard failure — per-slice top-100 + merge is exact). NO fence/last-block
// tricks (R3 lesson: device-scope fences cost tens of us on 8-XCD MI355X).
// Inner rank loop 8-way unrolled: 8 independent ds_reads per group breaks the
// ~120-cy single-outstanding LDS latency chain (R2/R0 diagnosis).
// ===========================================================================
__global__ __launch_bounds__(256) void rank_kernel(
    const float* __restrict__ docs, const double* __restrict__ proto,
    const unsigned short* __restrict__ Thi,
    const unsigned* __restrict__ shardCnt, const unsigned* __restrict__ strictSh,
    const unsigned* __restrict__ candIdx, unsigned* __restrict__ rscratch,
    double* __restrict__ stD2, unsigned* __restrict__ stIx,
    unsigned* __restrict__ stLen, int N) {
    const int sh = blockIdx.x, s = blockIdx.y, t = threadIdx.x;
    __shared__ double   ld[SHCAP];
    __shared__ unsigned li[SHCAP];
    __shared__ double   ps[DDIM];
    __shared__ double   outD2[KSEL];
    __shared__ unsigned outIx[KSEL];
    __shared__ unsigned c_s, rcnt;
    __shared__ int      prim_s;

    if (t < DDIM) ps[t] = proto[s * DDIM + t];
    if (t == 0) { prim_s = slate_use_primary(shardCnt, strictSh, s); rcnt = 0u; }
    __syncthreads();

    // ---- gather candidates for this (s,sh) into LDS with exact f64 d2 ----
    unsigned c;
    if (prim_s) {
        if (t == 0) {
            unsigned cc = shardCnt[(sh * SLATE + s) * 16];
            c_s = cc > SHCAP ? SHCAP : cc;          // unreachable clamp (guard)
        }
        __syncthreads();
        c = c_s;
        const unsigned* src = candIdx + ((size_t)(s * NSH + sh)) * SHCAP;
        for (unsigned i = t; i < c; i += 256) {
            unsigned idx = src[i];
            li[i] = idx;
            float doc[DDIM];
            load_doc(docs, (size_t)idx, doc);
            ld[i] = calc_d2(doc, ps);               // canonical exact d2
        }
    } else {
        // exact recovery scan over this block's doc slice
        unsigned kt = Thi[s];
        unsigned* lst = rscratch + (size_t)s * RCAP + (size_t)sh * SHCAP;
        int lo = (int)((long long)N * sh / NSH);
        int hi = (int)((long long)N * (sh + 1) / NSH);
        for (int n = lo + t; n < hi; n += 256) {
            float doc[DDIM];
            load_doc(docs, (size_t)n, doc);
            double d2 = calc_d2(doc, ps);
            unsigned key = __float_as_uint((float)d2) >> 16;
            if (key <= kt) {
                unsigned pos = atomicAdd(&rcnt, 1u);
                if (pos < SHCAP) lst[pos] = (unsigned)n;
            }
        }
        __syncthreads();
        c = rcnt < SHCAP ? rcnt : SHCAP;
        for (unsigned i = t; i < c; i += 256) {
            unsigned idx = lst[i];
            li[i] = idx;
            float doc[DDIM];
            load_doc(docs, (size_t)idx, doc);
            ld[i] = calc_d2(doc, ps);
        }
    }
    __syncthreads();

    // ---- exact local rank by (d2, idx); 8-way unrolled LDS compare loop ----
    for (unsigned e = t; e < c; e += 256) {
        double de = ld[e]; unsigned ie = li[e];
        unsigned rank = 0;
        unsigned j = 0;
        for (; j + 8 <= c; j += 8) {
            double d0 = ld[j+0], d1 = ld[j+1], d2 = ld[j+2], d3 = ld[j+3];
            double d4 = ld[j+4], d5 = ld[j+5], d6 = ld[j+6], d7 = ld[j+7];
            unsigned i0 = li[j+0], i1 = li[j+1], i2 = li[j+2], i3 = li[j+3];
            unsigned i4 = li[j+4], i5 = li[j+5], i6 = li[j+6], i7 = li[j+7];
            rank += ((d0 < de) || (d0 == de && i0 < ie))
                  + ((d1 < de) || (d1 == de && i1 < ie))
                  + ((d2 < de) || (d2 == de && i2 < ie))
                  + ((d3 < de) || (d3 == de && i3 < ie))
                  + ((d4 < de) || (d4 == de && i4 < ie))
                  + ((d5 < de) || (d5 == de && i5 < ie))
                  + ((d6 < de) || (d6 == de && i6 < ie))
                  + ((d7 < de) || (d7 == de && i7 < ie));
        }
        for (; j < c; ++j) {
            double dj = ld[j]; unsigned ij = li[j];
            rank += (dj < de) || (dj == de && ij < ie);
        }
        if (rank < KSEL) { outD2[rank] = de; outIx[rank] = ie; }
    }
    __syncthreads();

    unsigned L = c < KSEL ? c : KSEL;
    size_t base = (size_t)(s * NSH + sh) * STP;
    for (unsigned r = t; r < L; r += 256) {
        stD2[base + r] = outD2[r];
        stIx[base + r] = outIx[r];
    }
    if (t == 0) stLen[s * NSH + sh] = L;
}

// -------- Kernel 5: merge 8 sorted lists, interleaved binary searches -------
// The 7 other-list lower_bounds run in LOCKSTEP: each level issues 7
// independent ds_reads (vs 7 serial searches of dependent loads) — breaks the
// LDS latency chain the same way as rank's unroll.
__global__ __launch_bounds__(1024) void merge_kernel(
    const float* __restrict__ docs,
    const double* __restrict__ stD2, const unsigned* __restrict__ stIx,
    const unsigned* __restrict__ stLen, float* __restrict__ out) {
    int s = blockIdx.x, t = threadIdx.x;
    __shared__ double md[NSH * KSEL];
    __shared__ unsigned mi[NSH * KSEL];
    __shared__ unsigned Ls[NSH], offs[NSH + 1];
    __shared__ unsigned sel[KSEL];
    if (t < NSH) Ls[t] = stLen[s * NSH + t];
    __syncthreads();
    if (t == 0) {
        unsigned o = 0;
        for (int sh = 0; sh < NSH; ++sh) { offs[sh] = o; o += Ls[sh]; }
        offs[NSH] = o;
    }
    __syncthreads();
    for (int sh = 0; sh < NSH; ++sh) {
        unsigned L = Ls[sh];
        for (unsigned i = t; i < L; i += 1024) {
            md[sh * KSEL + i] = stD2[(size_t)(s * NSH + sh) * STP + i];
            mi[sh * KSEL + i] = stIx[(size_t)(s * NSH + sh) * STP + i];
        }
    }
    __syncthreads();

    unsigned S = offs[NSH];
    for (unsigned e = t; e < S; e += 1024) {
        // locate (shard, local pos)
        int sh = 0;
        while (e >= offs[sh + 1]) ++sh;
        unsigned i = e - offs[sh];
        double xd = md[sh * KSEL + i];
        unsigned xi = mi[sh * KSEL + i];
        // interleaved lower_bound by (d2, idx) across the 7 other lists
        unsigned lo[NSH], hi[NSH];
#pragma unroll
        for (int so = 0; so < NSH; ++so) { lo[so] = 0; hi[so] = (so == sh) ? 0u : Ls[so]; }
        bool active = true;
        while (active) {
            active = false;
            double   dj[NSH];
            unsigned ij[NSH], mid[NSH];
#pragma unroll
            for (int so = 0; so < NSH; ++so) {
                if (lo[so] < hi[so]) {
                    unsigned m = (lo[so] + hi[so]) >> 1;
                    mid[so] = m;
                    dj[so] = md[so * KSEL + m];     // independent loads, pipelined
                    ij[so] = mi[so * KSEL + m];
                }
            }
#pragma unroll
            for (int so = 0; so < NSH; ++so) {
                if (lo[so] < hi[so]) {
                    bool less = (dj[so] < xd) || (dj[so] == xd && ij[so] < xi);
                    if (less) lo[so] = mid[so] + 1; else hi[so] = mid[so];
                    if (lo[so] < hi[so]) active = true;
                }
            }
        }
        unsigned rank = i;                        // own sorted list: i smaller
#pragma unroll
        for (int so = 0; so < NSH; ++so) rank += lo[so];
        if (rank < KSEL) sel[rank] = xi;
    }
    __syncthreads();

    if (t < KSEL) out[(size_t)OUT_IDX_OFF + s * KSEL + t] = (float)sel[t];
    for (int pos = t; pos < KSEL * DDIM; pos += 1024) {
        int r = pos / DDIM, c = pos % DDIM;
        out[((size_t)s * KSEL + r) * DDIM + c] = docs[(size_t)sel[r] * DDIM + c];
    }
}

extern "C" void kernel_launch(void* const* d_in, const int* in_sizes, int n_in,
                              void* d_out, int out_size, void* d_ws, size_t ws_size,
                              hipStream_t stream) {
    const float* x0   = (const float*)d_in[0];
    const float* docs = (const float*)d_in[1];
    const float* W1   = (const float*)d_in[2];
    const float* b1   = (const float*)d_in[3];
    const float* W2   = (const float*)d_in[4];
    const float* b2   = (const float*)d_in[5];
    const float* W3   = (const float*)d_in[6];
    const float* b3   = (const float*)d_in[7];
    int N = in_sizes[1] / DDIM;   // 1,000,000

    char* ws = (char*)d_ws;
    double*         proto    = (double*)(ws + WS_PROTO);
    float*          protof   = (float*)(ws + WS_PROTOF);
    unsigned short* Tp2      = (unsigned short*)(ws + WS_TP2);
    unsigned short* Tm2      = (unsigned short*)(ws + WS_TM2);
    unsigned short* Thi      = (unsigned short*)(ws + WS_THI);
    unsigned*       shardCnt = (unsigned*)(ws + WS_SHCNT);
    unsigned*       strictSh = (unsigned*)(ws + WS_STRICT);
    unsigned short* skeys    = (unsigned short*)(ws + WS_SKEYS);
    unsigned*       candIdx  = (unsigned*)(ws + WS_CAND);
    unsigned*       rscratch = (unsigned*)(ws + WS_CAND2);
    double*         stD2     = (double*)(ws + WS_STD2);
    unsigned*       stIx     = (unsigned*)(ws + WS_STIX);
    unsigned*       stLen    = (unsigned*)(ws + WS_STLEN);
    float*          outp     = (float*)d_out;

    // 5 kernels / 4 boundaries. No cooperative launch (R1: grid.sync ~100us),
    // no device-scope fence patterns (R3: L2 writeback tens of us), no
    // hipMemsetAsync (zeroing fused into kernel 1).
    mlp_sample_kernel<<<SAMPN / 256 + 1, 256, 0, stream>>>(
        x0, docs, W1, b1, W2, b2, W3, b3, proto, protof, skeys, shardCnt, N);
    select_kernel<<<SLATE, 1024, 0, stream>>>(skeys, Tp2, Tm2, Thi);
    int nb = (N + 255) / 256;
    compact1_kernel<<<nb, 256, 0, stream>>>(docs, protof, Tp2, Tm2,
                                            shardCnt, strictSh, candIdx, N);
    rank_kernel<<<dim3(NSH, SLATE), 256, 0, stream>>>(
        docs, proto, Thi, shardCnt, strictSh, candIdx, rscratch,
        stD2, stIx, stLen, N);
    merge_kernel<<<SLATE, 1024, 0, stream>>>(docs, stD2, stIx, stLen, outp);
}